// Round 1
// baseline (2233.291 us; speedup 1.0000x reference)
//
#include <hip/hip_runtime.h>
#include <cstdint>
#include <cstddef>

// ---------------------------------------------------------------------------
// RNNAttentionModel: embed -> 2-layer tanh RNN scan -> causal self-attention
// (materialized scores, bf16 MFMA GEMMs) -> concat -> FC(55)
// B=64 T=1024 E=64 H=128 V=55
// ---------------------------------------------------------------------------

#define Bsz 64
#define Tsz 1024
#define Esz 64
#define Hsz 128
#define Vsz 55

typedef __attribute__((ext_vector_type(8))) short short8;   // 8 x bf16 frag
typedef __attribute__((ext_vector_type(4))) float f32x4;

__device__ __forceinline__ float bf2f(unsigned short u) {
    union { unsigned int i; float f; } c; c.i = ((unsigned int)u) << 16; return c.f;
}
__device__ __forceinline__ unsigned short f2bf(float f) {
    union { float f; unsigned int i; } c; c.f = f;
    unsigned int u = c.i;
    u += 0x7fffu + ((u >> 16) & 1u);   // RNE
    return (unsigned short)(u >> 16);
}
__device__ __forceinline__ float fast_tanh(float x) {
    float e = __expf(2.0f * x);
    return 1.0f - 2.0f / (e + 1.0f);
}

// ---------------------------------------------------------------------------
// K1: serial RNN scan, one block per batch element. Embedding + x@w_ih0.T
// folded into stage A. Weights live in VGPRs (224 floats/thread).
// thread (i = tid&127, half = tid>>7): owns half-row i of each weight matrix.
// ---------------------------------------------------------------------------
__global__ __launch_bounds__(256, 1)
void k_scan(const int* __restrict__ x, const float* __restrict__ emb,
            const float* __restrict__ w_ih0, const float* __restrict__ b_ih0,
            const float* __restrict__ w_hh0, const float* __restrict__ b_hh0,
            const float* __restrict__ w_ih1, const float* __restrict__ b_ih1,
            const float* __restrict__ w_hh1, const float* __restrict__ b_hh1,
            unsigned short* __restrict__ outs_bf)
{
    const int tid  = threadIdx.x;
    const int i    = tid & 127;
    const int half = tid >> 7;
    const int b    = blockIdx.x;

    __shared__ float h0s[128];
    __shared__ float h1s[128];
    __shared__ float es[2][64];
    __shared__ float part[256];
    __shared__ int   xs[1024];

    float w0[64], w1[64], w2[64], wi0[32];
    {
        const float4* p0 = (const float4*)(w_hh0 + i * 128 + half * 64);
        const float4* p1 = (const float4*)(w_ih1 + i * 128 + half * 64);
        const float4* p2 = (const float4*)(w_hh1 + i * 128 + half * 64);
#pragma unroll
        for (int j = 0; j < 16; ++j) {
            float4 a = p0[j]; w0[4*j]=a.x; w0[4*j+1]=a.y; w0[4*j+2]=a.z; w0[4*j+3]=a.w;
            float4 c = p1[j]; w1[4*j]=c.x; w1[4*j+1]=c.y; w1[4*j+2]=c.z; w1[4*j+3]=c.w;
            float4 d = p2[j]; w2[4*j]=d.x; w2[4*j+1]=d.y; w2[4*j+2]=d.z; w2[4*j+3]=d.w;
        }
        const float4* p3 = (const float4*)(w_ih0 + i * 64 + half * 32);
#pragma unroll
        for (int j = 0; j < 8; ++j) {
            float4 a = p3[j]; wi0[4*j]=a.x; wi0[4*j+1]=a.y; wi0[4*j+2]=a.z; wi0[4*j+3]=a.w;
        }
    }
    float bias0 = 0.f, bias1 = 0.f;
    if (tid < 128) { bias0 = b_ih0[i] + b_hh0[i]; bias1 = b_ih1[i] + b_hh1[i]; }

    for (int k = tid; k < 1024; k += 256) xs[k] = x[b * 1024 + k];
    if (tid < 128) { h0s[tid] = 0.f; h1s[tid] = 0.f; }
    __syncthreads();
    if (tid < 64) es[0][tid] = emb[xs[0] * 64 + tid];
    __syncthreads();

    for (int t = 0; t < 1024; ++t) {
        const int buf = t & 1;
        const float* h0h = h0s + half * 64;
        const float* h1h = h1s + half * 64;
        const float* eh  = es[buf] + half * 32;

        // ---- stage A: partial of w_hh0 @ h0 + w_ih0 @ e_t (4 accum chains)
        float s0 = 0.f, s1 = 0.f, s2 = 0.f, s3 = 0.f;
#pragma unroll
        for (int j = 0; j < 16; ++j) {
            s0 += w0[4*j]   * h0h[4*j];
            s1 += w0[4*j+1] * h0h[4*j+1];
            s2 += w0[4*j+2] * h0h[4*j+2];
            s3 += w0[4*j+3] * h0h[4*j+3];
        }
#pragma unroll
        for (int j = 0; j < 8; ++j) {
            s0 += wi0[4*j]   * eh[4*j];
            s1 += wi0[4*j+1] * eh[4*j+1];
            s2 += wi0[4*j+2] * eh[4*j+2];
            s3 += wi0[4*j+3] * eh[4*j+3];
        }
        part[tid] = (s0 + s1) + (s2 + s3);
        __syncthreads();                       // B1
        if (tid < 128) {
            float v = bias0 + part[i] + part[i + 128];
            h0s[i] = fast_tanh(v);
        }
        __syncthreads();                       // B2

        // prefetch next embedding row (overlaps stage B)
        if (t + 1 < 1024 && tid >= 128 && tid < 192)
            es[buf ^ 1][tid - 128] = emb[xs[t + 1] * 64 + (tid - 128)];

        // ---- stage B: partial of w_ih1 @ h0_new + w_hh1 @ h1
        float u0 = 0.f, u1 = 0.f, u2 = 0.f, u3 = 0.f;
#pragma unroll
        for (int j = 0; j < 16; ++j) {
            u0 += w1[4*j]   * h0h[4*j]   + w2[4*j]   * h1h[4*j];
            u1 += w1[4*j+1] * h0h[4*j+1] + w2[4*j+1] * h1h[4*j+1];
            u2 += w1[4*j+2] * h0h[4*j+2] + w2[4*j+2] * h1h[4*j+2];
            u3 += w1[4*j+3] * h0h[4*j+3] + w2[4*j+3] * h1h[4*j+3];
        }
        part[tid] = (u0 + u1) + (u2 + u3);
        __syncthreads();                       // B3
        if (tid < 128) {
            float v  = bias1 + part[i] + part[i + 128];
            float h1 = fast_tanh(v);
            h1s[i] = h1;
            outs_bf[((size_t)b * 1024 + t) * 128 + i] = f2bf(h1);
        }
        __syncthreads();                       // B4
    }
}

// ---------------------------------------------------------------------------
// K2: outs [b][t][h] -> outsT [b][h][t]  (LDS tile transpose)
// ---------------------------------------------------------------------------
__global__ __launch_bounds__(256)
void k_transpose(const unsigned short* __restrict__ outs_bf,
                 unsigned short* __restrict__ outsT)
{
    __shared__ unsigned short lt[128][130];
    const int tid = threadIdx.x;
    const int t0  = blockIdx.x * 128;
    const int b   = blockIdx.y;
    const unsigned int* src =
        (const unsigned int*)(outs_bf + ((size_t)b * 1024 + t0) * 128);
    for (int idx = tid; idx < 8192; idx += 256) {
        int tr = idx >> 6, h2 = idx & 63;
        unsigned int v = src[tr * 64 + h2];
        lt[tr][h2 * 2]     = (unsigned short)(v & 0xffffu);
        lt[tr][h2 * 2 + 1] = (unsigned short)(v >> 16);
    }
    __syncthreads();
    unsigned int* dst = (unsigned int*)(outsT + (size_t)b * 128 * 1024);
    for (int idx = tid; idx < 8192; idx += 256) {
        int h = idx >> 6, t2 = idx & 63;
        unsigned int v = (unsigned int)lt[t2 * 2][h] |
                         ((unsigned int)lt[t2 * 2 + 1][h] << 16);
        dst[h * 512 + (t0 >> 1) + t2] = v;
    }
}

// ---------------------------------------------------------------------------
// MFMA GEMM core conventions (16x16x32 bf16):
//   A frag: lane holds A[m=16*tile+(lane&15)][k = 8*(lane>>4) .. +7]
//   B frag: lane holds B[k][n] gathered as Brow[n=16*tile+(lane&15)][same k]
//   C/D   : col = lane&15, row = 4*(lane>>4) + reg
// LDS layout [row][k], 16B chunks XOR-swizzled: phys_k8 = k8 ^ (row & mask)
// ---------------------------------------------------------------------------

// K3: Q = outs @ attn_w.T + attn_b   (M = B*T, N = K = 128, one LDS pass)
__global__ __launch_bounds__(256, 2)
void k_qproj(const unsigned short* __restrict__ outs_bf,
             const float* __restrict__ attn_w, const float* __restrict__ attn_b,
             unsigned short* __restrict__ q_bf)
{
    __shared__ __align__(16) unsigned short lA[128 * 128];
    __shared__ __align__(16) unsigned short lB[128 * 128];
    const int tid   = threadIdx.x;
    const int mbase = blockIdx.x * 128;

    for (int c = tid; c < 2048; c += 256) {
        int row = c >> 4, k8 = c & 15;
        uint4 v = *(const uint4*)(outs_bf + ((size_t)(mbase + row)) * 128 + k8 * 8);
        *(uint4*)&lA[row * 128 + ((k8 ^ (row & 15)) << 3)] = v;
    }
    for (int c = tid; c < 2048; c += 256) {
        int row = c >> 4, k8 = c & 15;
        const float4* p = (const float4*)(attn_w + row * 128 + k8 * 8);
        float4 f0 = p[0], f1 = p[1];
        uint4 vv;
        vv.x = (unsigned int)f2bf(f0.x) | ((unsigned int)f2bf(f0.y) << 16);
        vv.y = (unsigned int)f2bf(f0.z) | ((unsigned int)f2bf(f0.w) << 16);
        vv.z = (unsigned int)f2bf(f1.x) | ((unsigned int)f2bf(f1.y) << 16);
        vv.w = (unsigned int)f2bf(f1.z) | ((unsigned int)f2bf(f1.w) << 16);
        *(uint4*)&lB[row * 128 + ((k8 ^ (row & 15)) << 3)] = vv;
    }
    __syncthreads();

    const int w = tid >> 6, lane = tid & 63, quad = lane >> 4, l16 = lane & 15;
    f32x4 acc[2][8];
#pragma unroll
    for (int r = 0; r < 2; ++r)
#pragma unroll
        for (int n = 0; n < 8; ++n) acc[r][n] = (f32x4){0.f, 0.f, 0.f, 0.f};

#pragma unroll
    for (int ks = 0; ks < 4; ++ks) {
        int k8 = ks * 4 + quad;
        short8 af[2];
#pragma unroll
        for (int r = 0; r < 2; ++r) {
            int row = w * 32 + r * 16 + l16;
            af[r] = *(const short8*)&lA[row * 128 + ((k8 ^ (row & 15)) << 3)];
        }
        short8 bfr[8];
#pragma unroll
        for (int n = 0; n < 8; ++n) {
            int col = n * 16 + l16;
            bfr[n] = *(const short8*)&lB[col * 128 + ((k8 ^ (col & 15)) << 3)];
        }
#pragma unroll
        for (int r = 0; r < 2; ++r)
#pragma unroll
            for (int n = 0; n < 8; ++n)
                acc[r][n] = __builtin_amdgcn_mfma_f32_16x16x32_bf16(
                    af[r], bfr[n], acc[r][n], 0, 0, 0);
    }
#pragma unroll
    for (int n = 0; n < 8; ++n) {
        int col = n * 16 + l16;
        float bias = attn_b[col];
#pragma unroll
        for (int r = 0; r < 2; ++r)
#pragma unroll
            for (int reg = 0; reg < 4; ++reg) {
                int row = w * 32 + r * 16 + quad * 4 + reg;
                q_bf[((size_t)(mbase + row)) * 128 + col] =
                    f2bf(acc[r][n][reg] + bias);
            }
    }
}

// K4: scores[b][q][k] = (Q[b][q] . outs[b][k]) / sqrt(H), causal tiles only
__global__ __launch_bounds__(256, 2)
void k_scores(const unsigned short* __restrict__ q_bf,
              const unsigned short* __restrict__ outs_bf,
              unsigned short* __restrict__ sc, int b0)
{
    const int kt = blockIdx.x, qt = blockIdx.y, bl = blockIdx.z;
    if (kt > qt) return;
    const int b = b0 + bl;

    __shared__ __align__(16) unsigned short lA[128 * 128];
    __shared__ __align__(16) unsigned short lB[128 * 128];
    const int tid = threadIdx.x;

    for (int c = tid; c < 2048; c += 256) {
        int row = c >> 4, k8 = c & 15;
        uint4 va = *(const uint4*)(q_bf +
            ((size_t)(b * 1024 + qt * 128 + row)) * 128 + k8 * 8);
        *(uint4*)&lA[row * 128 + ((k8 ^ (row & 15)) << 3)] = va;
        uint4 vb = *(const uint4*)(outs_bf +
            ((size_t)(b * 1024 + kt * 128 + row)) * 128 + k8 * 8);
        *(uint4*)&lB[row * 128 + ((k8 ^ (row & 15)) << 3)] = vb;
    }
    __syncthreads();

    const int w = tid >> 6, lane = tid & 63, quad = lane >> 4, l16 = lane & 15;
    f32x4 acc[2][8];
#pragma unroll
    for (int r = 0; r < 2; ++r)
#pragma unroll
        for (int n = 0; n < 8; ++n) acc[r][n] = (f32x4){0.f, 0.f, 0.f, 0.f};

#pragma unroll
    for (int ks = 0; ks < 4; ++ks) {
        int k8 = ks * 4 + quad;
        short8 af[2];
#pragma unroll
        for (int r = 0; r < 2; ++r) {
            int row = w * 32 + r * 16 + l16;
            af[r] = *(const short8*)&lA[row * 128 + ((k8 ^ (row & 15)) << 3)];
        }
        short8 bfr[8];
#pragma unroll
        for (int n = 0; n < 8; ++n) {
            int col = n * 16 + l16;
            bfr[n] = *(const short8*)&lB[col * 128 + ((k8 ^ (col & 15)) << 3)];
        }
#pragma unroll
        for (int r = 0; r < 2; ++r)
#pragma unroll
            for (int n = 0; n < 8; ++n)
                acc[r][n] = __builtin_amdgcn_mfma_f32_16x16x32_bf16(
                    af[r], bfr[n], acc[r][n], 0, 0, 0);
    }
    const float scale = 0.08838834764831845f;  // 1/sqrt(128)
#pragma unroll
    for (int n = 0; n < 8; ++n) {
        int col = n * 16 + l16;
#pragma unroll
        for (int r = 0; r < 2; ++r)
#pragma unroll
            for (int reg = 0; reg < 4; ++reg) {
                int row = w * 32 + r * 16 + quad * 4 + reg;
                sc[((size_t)(bl * 1024 + qt * 128 + row)) * 1024 + kt * 128 + col] =
                    f2bf(acc[r][n][reg] * scale);
            }
    }
}

// K5: causal softmax in place (bf16), zero-fill up to written tile boundary
__global__ __launch_bounds__(256)
void k_softmax(unsigned short* __restrict__ sc)
{
    const int tid = threadIdx.x, w = tid >> 6, lane = tid & 63;
    const int r = blockIdx.x * 4 + w;           // row within chunk
    const int q = r & 1023;
    unsigned int* row = (unsigned int*)sc + (size_t)r * 512;
    const int nIter = (q >> 7) + 1;             // 128-element groups written

    float m = -1e30f, l = 0.f;
    for (int ii = 0; ii < nIter; ++ii) {
        int k2 = lane + (ii << 6);
        unsigned int u = row[k2];
        float a  = bf2f((unsigned short)(u & 0xffffu));
        float bq = bf2f((unsigned short)(u >> 16));
        float mt = fmaxf((2 * k2 <= q) ? a : -1e30f,
                         (2 * k2 + 1 <= q) ? bq : -1e30f);
        float mn = fmaxf(m, mt);
        float ea = (2 * k2     <= q) ? __expf(a  - mn) : 0.f;
        float eb = (2 * k2 + 1 <= q) ? __expf(bq - mn) : 0.f;
        l = l * __expf(m - mn) + ea + eb;
        m = mn;
    }
#pragma unroll
    for (int off = 1; off < 64; off <<= 1) {
        float m2 = __shfl_xor(m, off, 64);
        float l2 = __shfl_xor(l, off, 64);
        float mn = fmaxf(m, m2);
        l = l * __expf(m - mn) + l2 * __expf(m2 - mn);
        m = mn;
    }
    float inv = 1.0f / l;
    for (int ii = 0; ii < nIter; ++ii) {
        int k2 = lane + (ii << 6);
        unsigned int u = row[k2];
        float a  = bf2f((unsigned short)(u & 0xffffu));
        float bq = bf2f((unsigned short)(u >> 16));
        float pa = (2 * k2     <= q) ? __expf(a  - m) * inv : 0.f;
        float pb = (2 * k2 + 1 <= q) ? __expf(bq - m) * inv : 0.f;
        row[k2] = (unsigned int)f2bf(pa) | ((unsigned int)f2bf(pb) << 16);
    }
}

// K6: ctx[b][q][d] = P[b][q][s] @ V[s][d]  (V = outs, B-frag from outsT)
__global__ __launch_bounds__(256, 2)
void k_pv(const unsigned short* __restrict__ pr,
          const unsigned short* __restrict__ outsT,
          float* __restrict__ ctx, int b0)
{
    const int qt = blockIdx.x, bl = blockIdx.y;
    const int b = b0 + bl;
    __shared__ __align__(16) unsigned short lA[128 * 64];
    __shared__ __align__(16) unsigned short lB[128 * 64];
    const int tid = threadIdx.x;
    const int w = tid >> 6, lane = tid & 63, quad = lane >> 4, l16 = lane & 15;

    f32x4 acc[2][8];
#pragma unroll
    for (int r = 0; r < 2; ++r)
#pragma unroll
        for (int n = 0; n < 8; ++n) acc[r][n] = (f32x4){0.f, 0.f, 0.f, 0.f};

    const int stmax = 2 * qt + 1;
    for (int st = 0; st <= stmax; ++st) {
        __syncthreads();
        for (int c = tid; c < 1024; c += 256) {
            int row = c >> 3, k8 = c & 7;
            uint4 va = *(const uint4*)(pr +
                ((size_t)(bl * 1024 + qt * 128 + row)) * 1024 + st * 64 + k8 * 8);
            *(uint4*)&lA[row * 64 + ((k8 ^ (row & 7)) << 3)] = va;
            uint4 vb = *(const uint4*)(outsT +
                ((size_t)(b * 128 + row)) * 1024 + st * 64 + k8 * 8);
            *(uint4*)&lB[row * 64 + ((k8 ^ (row & 7)) << 3)] = vb;
        }
        __syncthreads();
#pragma unroll
        for (int ks = 0; ks < 2; ++ks) {
            int k8 = ks * 4 + quad;
            short8 af[2];
#pragma unroll
            for (int r = 0; r < 2; ++r) {
                int row = w * 32 + r * 16 + l16;
                af[r] = *(const short8*)&lA[row * 64 + ((k8 ^ (row & 7)) << 3)];
            }
            short8 bfr[8];
#pragma unroll
            for (int n = 0; n < 8; ++n) {
                int col = n * 16 + l16;
                bfr[n] = *(const short8*)&lB[col * 64 + ((k8 ^ (col & 7)) << 3)];
            }
#pragma unroll
            for (int r = 0; r < 2; ++r)
#pragma unroll
                for (int n = 0; n < 8; ++n)
                    acc[r][n] = __builtin_amdgcn_mfma_f32_16x16x32_bf16(
                        af[r], bfr[n], acc[r][n], 0, 0, 0);
        }
    }
#pragma unroll
    for (int n = 0; n < 8; ++n) {
        int col = n * 16 + l16;
#pragma unroll
        for (int r = 0; r < 2; ++r)
#pragma unroll
            for (int reg = 0; reg < 4; ++reg) {
                int row = w * 32 + r * 16 + quad * 4 + reg;
                ctx[((size_t)(b * 1024) + qt * 128 + row) * 128 + col] =
                    acc[r][n][reg];
            }
    }
}

// K7: logits = [outs | ctx] @ fc_w.T + fc_b   (V=55, K=256)
__global__ __launch_bounds__(256, 2)
void k_fc(const unsigned short* __restrict__ outs_bf,
          const float* __restrict__ ctx,
          const float* __restrict__ fc_w, const float* __restrict__ fc_b,
          float* __restrict__ out)
{
    __shared__ float lw[55 * 257];
    __shared__ float comb[256];
    __shared__ float part[256];
    const int tid = threadIdx.x;
    const int c = tid >> 6, v = tid & 63;

    for (int idx = tid; idx < 55 * 256; idx += 256) {
        int rr = idx >> 8, cc = idx & 255;
        lw[rr * 257 + cc] = fc_w[idx];
    }
    __syncthreads();

    const int t0 = blockIdx.x * 64;
    for (int t = 0; t < 64; ++t) {
        size_t bt = (size_t)(t0 + t);
        if (tid < 128) comb[tid] = bf2f(outs_bf[bt * 128 + tid]);
        else           comb[tid] = ctx[bt * 128 + (tid - 128)];
        __syncthreads();
        float p0 = 0.f, p1 = 0.f, p2 = 0.f, p3 = 0.f;
        if (v < 55) {
            const float* wr = lw + v * 257 + c * 64;
            const float* cb = comb + c * 64;
#pragma unroll
            for (int j = 0; j < 16; ++j) {
                p0 += wr[4*j]   * cb[4*j];
                p1 += wr[4*j+1] * cb[4*j+1];
                p2 += wr[4*j+2] * cb[4*j+2];
                p3 += wr[4*j+3] * cb[4*j+3];
            }
        }
        part[tid] = (p0 + p1) + (p2 + p3);
        __syncthreads();
        if (tid < 55) {
            out[bt * 55 + tid] = fc_b[tid] + part[tid] + part[64 + tid] +
                                 part[128 + tid] + part[192 + tid];
        }
        __syncthreads();
    }
}

// ---------------------------------------------------------------------------
extern "C" void kernel_launch(void* const* d_in, const int* in_sizes, int n_in,
                              void* d_out, int out_size, void* d_ws, size_t ws_size,
                              hipStream_t stream)
{
    const int*   x      = (const int*)d_in[0];
    const float* emb    = (const float*)d_in[1];
    const float* w_ih0  = (const float*)d_in[2];
    const float* b_ih0  = (const float*)d_in[3];
    const float* w_hh0  = (const float*)d_in[4];
    const float* b_hh0  = (const float*)d_in[5];
    const float* w_ih1  = (const float*)d_in[6];
    const float* b_ih1  = (const float*)d_in[7];
    const float* w_hh1  = (const float*)d_in[8];
    const float* b_hh1  = (const float*)d_in[9];
    const float* attn_w = (const float*)d_in[10];
    const float* attn_b = (const float*)d_in[11];
    const float* fc_w   = (const float*)d_in[12];
    const float* fc_b   = (const float*)d_in[13];
    float* out = (float*)d_out;

    char* ws = (char*)d_ws;
    unsigned short* outs_bf = (unsigned short*)(ws);                        // 16 MiB
    unsigned short* outsT   = (unsigned short*)(ws + ((size_t)16 << 20));   // 16 MiB
    unsigned short* q_bf    = (unsigned short*)(ws + ((size_t)32 << 20));   // 16 MiB
    float*          ctx     = (float*)         (ws + ((size_t)48 << 20));   // 32 MiB
    unsigned short* sc      = (unsigned short*)(ws + ((size_t)80 << 20));   // CB*2 MiB

    size_t fixed = (size_t)80 << 20;
    size_t avail = (ws_size > fixed) ? (ws_size - fixed) : 0;
    int CB = (int)(avail / ((size_t)2 << 20));
    if (CB < 1)  CB = 1;
    if (CB > 64) CB = 64;

    k_scan<<<dim3(64), dim3(256), 0, stream>>>(
        x, emb, w_ih0, b_ih0, w_hh0, b_hh0, w_ih1, b_ih1, w_hh1, b_hh1, outs_bf);
    k_transpose<<<dim3(8, 64), dim3(256), 0, stream>>>(outs_bf, outsT);
    k_qproj<<<dim3(512), dim3(256), 0, stream>>>(outs_bf, attn_w, attn_b, q_bf);

    for (int b0 = 0; b0 < 64; b0 += CB) {
        int nb = 64 - b0; if (nb > CB) nb = CB;
        k_scores <<<dim3(8, 8, nb), dim3(256), 0, stream>>>(q_bf, outs_bf, sc, b0);
        k_softmax<<<dim3(nb * 256), dim3(256), 0, stream>>>(sc);
        k_pv     <<<dim3(8, nb),   dim3(256), 0, stream>>>(sc, outsT, ctx, b0);
    }
    k_fc<<<dim3(1024), dim3(256), 0, stream>>>(outs_bf, ctx, fc_w, fc_b, out);
}

// Round 2
// 1237.175 us; speedup vs baseline: 1.8052x; 1.8052x over previous
//
#include <hip/hip_runtime.h>
#include <cstdint>
#include <cstddef>

// ---------------------------------------------------------------------------
// RNNAttentionModel: embed -> 2-layer tanh RNN scan -> causal self-attention
// (materialized scores, bf16 MFMA GEMMs) -> concat -> FC(55)
// B=64 T=1024 E=64 H=128 V=55
// ---------------------------------------------------------------------------

typedef __attribute__((ext_vector_type(8))) short short8;   // 8 x bf16 frag
typedef __attribute__((ext_vector_type(4))) float f32x4;

__device__ __forceinline__ float bf2f(unsigned short u) {
    union { unsigned int i; float f; } c; c.i = ((unsigned int)u) << 16; return c.f;
}
__device__ __forceinline__ unsigned short f2bf(float f) {
    union { float f; unsigned int i; } c; c.f = f;
    unsigned int u = c.i;
    u += 0x7fffu + ((u >> 16) & 1u);   // RNE
    return (unsigned short)(u >> 16);
}
__device__ __forceinline__ float fast_tanh(float x) {
    float e = __expf(2.0f * x);
    return 1.0f - 2.0f / (e + 1.0f);
}
// Raw workgroup barrier: waits LDS ops only; global loads/stores stay in
// flight (avoids the vmcnt(0) drain __syncthreads() would emit every step).
__device__ __forceinline__ void bar_lds() {
    asm volatile("s_waitcnt lgkmcnt(0)\n\ts_barrier" ::: "memory");
}

// ---------------------------------------------------------------------------
// K0: WE[v][i] = w_ih0[i,:] . emb[v,:] + b_ih0[i] + b_hh0[i]   (55 x 128)
// ---------------------------------------------------------------------------
__global__ __launch_bounds__(128)
void k_we(const float* __restrict__ emb, const float* __restrict__ w_ih0,
          const float* __restrict__ b_ih0, const float* __restrict__ b_hh0,
          float* __restrict__ WE)
{
    __shared__ float ev[64];
    const int i = threadIdx.x;
    const int v = blockIdx.x;
    if (i < 64) ev[i] = emb[v * 64 + i];
    __syncthreads();
    float s = b_ih0[i] + b_hh0[i];
    const float* wr = w_ih0 + i * 64;
#pragma unroll
    for (int k = 0; k < 64; ++k) s += wr[k] * ev[k];
    WE[v * 128 + i] = s;
}

// ---------------------------------------------------------------------------
// K1: serial RNN scan, one block/batch, 512 threads = 4 A-waves + 4 B-waves.
//   A-waves (w 0..3): h0(t+1) = tanh(W_hh0 @ h0(t) + WE[x[t+1]])
//   B-waves (w 4..7): h1(t)   = tanh(W_ih1 @ h0(t) + W_hh1 @ h1(t-1) + b1)
// Both consume only post-barrier state {h0(t), h1(t-1)} -> ONE barrier/step.
// Row owned by 2 lanes of one wave (k-split, shfl_xor reduce). Double-buffered
// h state (no WAR). h1 staged in LDS ring, flushed 32 steps at a time.
// ---------------------------------------------------------------------------
__global__ __launch_bounds__(512, 2)
void k_scan2(const int* __restrict__ x, const float* __restrict__ WE,
             const float* __restrict__ w_hh0,
             const float* __restrict__ w_ih1, const float* __restrict__ b_ih1,
             const float* __restrict__ w_hh1, const float* __restrict__ b_hh1,
             unsigned short* __restrict__ outs_bf)
{
    const int tid = threadIdx.x;
    const int w   = tid >> 6;
    const int l   = tid & 63;
    const int row = ((w & 3) << 5) | (l & 31);
    const int kh  = l >> 5;              // k-half: 0 -> k 0..63, 1 -> k 64..127
    const int b   = blockIdx.x;

    __shared__ float h0buf[2][128];
    __shared__ float h1buf[2][128];
    __shared__ int   xs[1024];
    __shared__ __align__(16) unsigned short obuf[2][32][128];

    for (int k = tid; k < 1024; k += 512) xs[k] = x[b * 1024 + k];
    if (tid < 128) h1buf[0][tid] = 0.f;

    if (w < 4) {
        // ---------------- A-waves ----------------
        float wa[64];
        const float4* p0 = (const float4*)(w_hh0 + row * 128 + (kh << 6));
#pragma unroll
        for (int j = 0; j < 16; ++j) {
            float4 a = p0[j];
            wa[4*j]=a.x; wa[4*j+1]=a.y; wa[4*j+2]=a.z; wa[4*j+3]=a.w;
        }
        __syncthreads();                 // xs + h1 zero visible
        float we_cur = 0.f;
        if (l < 32) {
            h0buf[0][row] = fast_tanh(WE[xs[0] * 128 + row]);  // h0(0), prev=0
            we_cur = WE[xs[1] * 128 + row];                    // for t=0 use
        }
        bar_lds();                       // publish h0(0)

        for (int t = 0; t < 1024; ++t) {
            const int p = t & 1;
            if (t < 1023) {
                float s0=0.f, s1=0.f, s2=0.f, s3=0.f;
                const float4* h4 = (const float4*)&h0buf[p][kh << 6];
#pragma unroll
                for (int j = 0; j < 16; ++j) {
                    float4 hv = h4[j];
                    s0 += wa[4*j]   * hv.x;
                    s1 += wa[4*j+1] * hv.y;
                    s2 += wa[4*j+2] * hv.z;
                    s3 += wa[4*j+3] * hv.w;
                }
                float s = (s0 + s1) + (s2 + s3);
                s += __shfl_xor(s, 32);
                if (l < 32) {
                    h0buf[p ^ 1][row] = fast_tanh(s + we_cur);
                    if (t + 2 < 1024) we_cur = WE[xs[t + 2] * 128 + row];
                }
            }
            bar_lds();
            if ((t & 31) == 31) {        // cooperative flush (no barrier inside)
                const uint4* src = (const uint4*)&obuf[(t >> 5) & 1][0][0];
                uint4 v = src[tid];
                *((uint4*)(outs_bf + (size_t)b * 131072 +
                           (size_t)(t - 31) * 128) + tid) = v;
            }
        }
    } else {
        // ---------------- B-waves ----------------
        float wb0[64], wb1[64];
        const float4* p1 = (const float4*)(w_ih1 + row * 128 + (kh << 6));
        const float4* p2 = (const float4*)(w_hh1 + row * 128 + (kh << 6));
#pragma unroll
        for (int j = 0; j < 16; ++j) {
            float4 a = p1[j]; wb0[4*j]=a.x; wb0[4*j+1]=a.y; wb0[4*j+2]=a.z; wb0[4*j+3]=a.w;
            float4 c = p2[j]; wb1[4*j]=c.x; wb1[4*j+1]=c.y; wb1[4*j+2]=c.z; wb1[4*j+3]=c.w;
        }
        float b1v = b_ih1[row] + b_hh1[row];
        __syncthreads();                 // pairs with A's __syncthreads
        bar_lds();                       // pairs with A's post-prologue barrier

        for (int t = 0; t < 1024; ++t) {
            const int p = t & 1;
            float s0=0.f, s1=0.f, s2=0.f, s3=0.f;
            const float4* h4 = (const float4*)&h0buf[p][kh << 6];
            const float4* g4 = (const float4*)&h1buf[p][kh << 6];
#pragma unroll
            for (int j = 0; j < 16; ++j) {
                float4 hv = h4[j];
                float4 gv = g4[j];
                s0 += wb0[4*j]   * hv.x + wb1[4*j]   * gv.x;
                s1 += wb0[4*j+1] * hv.y + wb1[4*j+1] * gv.y;
                s2 += wb0[4*j+2] * hv.z + wb1[4*j+2] * gv.z;
                s3 += wb0[4*j+3] * hv.w + wb1[4*j+3] * gv.w;
            }
            float s = (s0 + s1) + (s2 + s3);
            s += __shfl_xor(s, 32);
            if (l < 32) {
                float h1 = fast_tanh(s + b1v);
                h1buf[p ^ 1][row] = h1;
                obuf[(t >> 5) & 1][t & 31][row] = f2bf(h1);
            }
            bar_lds();
            if ((t & 31) == 31) {
                const uint4* src = (const uint4*)&obuf[(t >> 5) & 1][0][0];
                uint4 v = src[tid];
                *((uint4*)(outs_bf + (size_t)b * 131072 +
                           (size_t)(t - 31) * 128) + tid) = v;
            }
        }
    }
}

// ---------------------------------------------------------------------------
// K2: outs [b][t][h] -> outsT [b][h][t]  (LDS tile transpose)
// ---------------------------------------------------------------------------
__global__ __launch_bounds__(256)
void k_transpose(const unsigned short* __restrict__ outs_bf,
                 unsigned short* __restrict__ outsT)
{
    __shared__ unsigned short lt[128][130];
    const int tid = threadIdx.x;
    const int t0  = blockIdx.x * 128;
    const int b   = blockIdx.y;
    const unsigned int* src =
        (const unsigned int*)(outs_bf + ((size_t)b * 1024 + t0) * 128);
    for (int idx = tid; idx < 8192; idx += 256) {
        int tr = idx >> 6, h2 = idx & 63;
        unsigned int v = src[tr * 64 + h2];
        lt[tr][h2 * 2]     = (unsigned short)(v & 0xffffu);
        lt[tr][h2 * 2 + 1] = (unsigned short)(v >> 16);
    }
    __syncthreads();
    unsigned int* dst = (unsigned int*)(outsT + (size_t)b * 128 * 1024);
    for (int idx = tid; idx < 8192; idx += 256) {
        int h = idx >> 6, t2 = idx & 63;
        unsigned int v = (unsigned int)lt[t2 * 2][h] |
                         ((unsigned int)lt[t2 * 2 + 1][h] << 16);
        dst[h * 512 + (t0 >> 1) + t2] = v;
    }
}

// ---------------------------------------------------------------------------
// MFMA GEMM core conventions (16x16x32 bf16):
//   A frag: lane holds A[m=16*tile+(lane&15)][k = 8*(lane>>4) .. +7]
//   B frag: lane holds B[k][n] gathered as Brow[n=16*tile+(lane&15)][same k]
//   C/D   : col = lane&15, row = 4*(lane>>4) + reg
// LDS layout [row][k], 16B chunks XOR-swizzled: phys_k8 = k8 ^ (row & mask)
// ---------------------------------------------------------------------------

// K3: Q = outs @ attn_w.T + attn_b   (M = B*T, N = K = 128, one LDS pass)
__global__ __launch_bounds__(256, 2)
void k_qproj(const unsigned short* __restrict__ outs_bf,
             const float* __restrict__ attn_w, const float* __restrict__ attn_b,
             unsigned short* __restrict__ q_bf)
{
    __shared__ __align__(16) unsigned short lA[128 * 128];
    __shared__ __align__(16) unsigned short lB[128 * 128];
    const int tid   = threadIdx.x;
    const int mbase = blockIdx.x * 128;

    for (int c = tid; c < 2048; c += 256) {
        int row = c >> 4, k8 = c & 15;
        uint4 v = *(const uint4*)(outs_bf + ((size_t)(mbase + row)) * 128 + k8 * 8);
        *(uint4*)&lA[row * 128 + ((k8 ^ (row & 15)) << 3)] = v;
    }
    for (int c = tid; c < 2048; c += 256) {
        int row = c >> 4, k8 = c & 15;
        const float4* p = (const float4*)(attn_w + row * 128 + k8 * 8);
        float4 f0 = p[0], f1 = p[1];
        uint4 vv;
        vv.x = (unsigned int)f2bf(f0.x) | ((unsigned int)f2bf(f0.y) << 16);
        vv.y = (unsigned int)f2bf(f0.z) | ((unsigned int)f2bf(f0.w) << 16);
        vv.z = (unsigned int)f2bf(f1.x) | ((unsigned int)f2bf(f1.y) << 16);
        vv.w = (unsigned int)f2bf(f1.z) | ((unsigned int)f2bf(f1.w) << 16);
        *(uint4*)&lB[row * 128 + ((k8 ^ (row & 15)) << 3)] = vv;
    }
    __syncthreads();

    const int w = tid >> 6, lane = tid & 63, quad = lane >> 4, l16 = lane & 15;
    f32x4 acc[2][8];
#pragma unroll
    for (int r = 0; r < 2; ++r)
#pragma unroll
        for (int n = 0; n < 8; ++n) acc[r][n] = (f32x4){0.f, 0.f, 0.f, 0.f};

#pragma unroll
    for (int ks = 0; ks < 4; ++ks) {
        int k8 = ks * 4 + quad;
        short8 af[2];
#pragma unroll
        for (int r = 0; r < 2; ++r) {
            int row = w * 32 + r * 16 + l16;
            af[r] = *(const short8*)&lA[row * 128 + ((k8 ^ (row & 15)) << 3)];
        }
        short8 bfr[8];
#pragma unroll
        for (int n = 0; n < 8; ++n) {
            int col = n * 16 + l16;
            bfr[n] = *(const short8*)&lB[col * 128 + ((k8 ^ (col & 15)) << 3)];
        }
#pragma unroll
        for (int r = 0; r < 2; ++r)
#pragma unroll
            for (int n = 0; n < 8; ++n)
                acc[r][n] = __builtin_amdgcn_mfma_f32_16x16x32_bf16(
                    af[r], bfr[n], acc[r][n], 0, 0, 0);
    }
#pragma unroll
    for (int n = 0; n < 8; ++n) {
        int col = n * 16 + l16;
        float bias = attn_b[col];
#pragma unroll
        for (int r = 0; r < 2; ++r)
#pragma unroll
            for (int reg = 0; reg < 4; ++reg) {
                int row = w * 32 + r * 16 + quad * 4 + reg;
                q_bf[((size_t)(mbase + row)) * 128 + col] =
                    f2bf(acc[r][n][reg] + bias);
            }
    }
}

// K4: scores[b][q][k] = (Q[b][q] . outs[b][k]) / sqrt(H), causal tiles only
__global__ __launch_bounds__(256, 2)
void k_scores(const unsigned short* __restrict__ q_bf,
              const unsigned short* __restrict__ outs_bf,
              unsigned short* __restrict__ sc, int b0)
{
    const int kt = blockIdx.x, qt = blockIdx.y, bl = blockIdx.z;
    if (kt > qt) return;
    const int b = b0 + bl;

    __shared__ __align__(16) unsigned short lA[128 * 128];
    __shared__ __align__(16) unsigned short lB[128 * 128];
    const int tid = threadIdx.x;

    for (int c = tid; c < 2048; c += 256) {
        int row = c >> 4, k8 = c & 15;
        uint4 va = *(const uint4*)(q_bf +
            ((size_t)(b * 1024 + qt * 128 + row)) * 128 + k8 * 8);
        *(uint4*)&lA[row * 128 + ((k8 ^ (row & 15)) << 3)] = va;
        uint4 vb = *(const uint4*)(outs_bf +
            ((size_t)(b * 1024 + kt * 128 + row)) * 128 + k8 * 8);
        *(uint4*)&lB[row * 128 + ((k8 ^ (row & 15)) << 3)] = vb;
    }
    __syncthreads();

    const int w = tid >> 6, lane = tid & 63, quad = lane >> 4, l16 = lane & 15;
    f32x4 acc[2][8];
#pragma unroll
    for (int r = 0; r < 2; ++r)
#pragma unroll
        for (int n = 0; n < 8; ++n) acc[r][n] = (f32x4){0.f, 0.f, 0.f, 0.f};

#pragma unroll
    for (int ks = 0; ks < 4; ++ks) {
        int k8 = ks * 4 + quad;
        short8 af[2];
#pragma unroll
        for (int r = 0; r < 2; ++r) {
            int row = w * 32 + r * 16 + l16;
            af[r] = *(const short8*)&lA[row * 128 + ((k8 ^ (row & 15)) << 3)];
        }
        short8 bfr[8];
#pragma unroll
        for (int n = 0; n < 8; ++n) {
            int col = n * 16 + l16;
            bfr[n] = *(const short8*)&lB[col * 128 + ((k8 ^ (col & 15)) << 3)];
        }
#pragma unroll
        for (int r = 0; r < 2; ++r)
#pragma unroll
            for (int n = 0; n < 8; ++n)
                acc[r][n] = __builtin_amdgcn_mfma_f32_16x16x32_bf16(
                    af[r], bfr[n], acc[r][n], 0, 0, 0);
    }
    const float scale = 0.08838834764831845f;  // 1/sqrt(128)
#pragma unroll
    for (int n = 0; n < 8; ++n) {
        int col = n * 16 + l16;
#pragma unroll
        for (int r = 0; r < 2; ++r)
#pragma unroll
            for (int reg = 0; reg < 4; ++reg) {
                int row = w * 32 + r * 16 + quad * 4 + reg;
                sc[((size_t)(bl * 1024 + qt * 128 + row)) * 1024 + kt * 128 + col] =
                    f2bf(acc[r][n][reg] * scale);
            }
    }
}

// K5: causal softmax in place (bf16)
__global__ __launch_bounds__(256)
void k_softmax(unsigned short* __restrict__ sc)
{
    const int tid = threadIdx.x, w = tid >> 6, lane = tid & 63;
    const int r = blockIdx.x * 4 + w;           // row within chunk
    const int q = r & 1023;
    unsigned int* row = (unsigned int*)sc + (size_t)r * 512;
    const int nIter = (q >> 7) + 1;             // 128-element groups written

    float m = -1e30f, l = 0.f;
    for (int ii = 0; ii < nIter; ++ii) {
        int k2 = lane + (ii << 6);
        unsigned int u = row[k2];
        float a  = bf2f((unsigned short)(u & 0xffffu));
        float bq = bf2f((unsigned short)(u >> 16));
        float mt = fmaxf((2 * k2 <= q) ? a : -1e30f,
                         (2 * k2 + 1 <= q) ? bq : -1e30f);
        float mn = fmaxf(m, mt);
        float ea = (2 * k2     <= q) ? __expf(a  - mn) : 0.f;
        float eb = (2 * k2 + 1 <= q) ? __expf(bq - mn) : 0.f;
        l = l * __expf(m - mn) + ea + eb;
        m = mn;
    }
#pragma unroll
    for (int off = 1; off < 64; off <<= 1) {
        float m2 = __shfl_xor(m, off, 64);
        float l2 = __shfl_xor(l, off, 64);
        float mn = fmaxf(m, m2);
        l = l * __expf(m - mn) + l2 * __expf(m2 - mn);
        m = mn;
    }
    float inv = 1.0f / l;
    for (int ii = 0; ii < nIter; ++ii) {
        int k2 = lane + (ii << 6);
        unsigned int u = row[k2];
        float a  = bf2f((unsigned short)(u & 0xffffu));
        float bq = bf2f((unsigned short)(u >> 16));
        float pa = (2 * k2     <= q) ? __expf(a  - m) * inv : 0.f;
        float pb = (2 * k2 + 1 <= q) ? __expf(bq - m) * inv : 0.f;
        row[k2] = (unsigned int)f2bf(pa) | ((unsigned int)f2bf(pb) << 16);
    }
}

// K6: ctx[b][q][d] = P[b][q][s] @ V[s][d]  (V = outs, B-frag from outsT)
__global__ __launch_bounds__(256, 2)
void k_pv(const unsigned short* __restrict__ pr,
          const unsigned short* __restrict__ outsT,
          float* __restrict__ ctx, int b0)
{
    const int qt = blockIdx.x, bl = blockIdx.y;
    const int b = b0 + bl;
    __shared__ __align__(16) unsigned short lA[128 * 64];
    __shared__ __align__(16) unsigned short lB[128 * 64];
    const int tid = threadIdx.x;
    const int w = tid >> 6, lane = tid & 63, quad = lane >> 4, l16 = lane & 15;

    f32x4 acc[2][8];
#pragma unroll
    for (int r = 0; r < 2; ++r)
#pragma unroll
        for (int n = 0; n < 8; ++n) acc[r][n] = (f32x4){0.f, 0.f, 0.f, 0.f};

    const int stmax = 2 * qt + 1;
    for (int st = 0; st <= stmax; ++st) {
        __syncthreads();
        for (int c = tid; c < 1024; c += 256) {
            int row = c >> 3, k8 = c & 7;
            uint4 va = *(const uint4*)(pr +
                ((size_t)(bl * 1024 + qt * 128 + row)) * 1024 + st * 64 + k8 * 8);
            *(uint4*)&lA[row * 64 + ((k8 ^ (row & 7)) << 3)] = va;
            uint4 vb = *(const uint4*)(outsT +
                ((size_t)(b * 128 + row)) * 1024 + st * 64 + k8 * 8);
            *(uint4*)&lB[row * 64 + ((k8 ^ (row & 7)) << 3)] = vb;
        }
        __syncthreads();
#pragma unroll
        for (int ks = 0; ks < 2; ++ks) {
            int k8 = ks * 4 + quad;
            short8 af[2];
#pragma unroll
            for (int r = 0; r < 2; ++r) {
                int row = w * 32 + r * 16 + l16;
                af[r] = *(const short8*)&lA[row * 64 + ((k8 ^ (row & 7)) << 3)];
            }
            short8 bfr[8];
#pragma unroll
            for (int n = 0; n < 8; ++n) {
                int col = n * 16 + l16;
                bfr[n] = *(const short8*)&lB[col * 64 + ((k8 ^ (col & 7)) << 3)];
            }
#pragma unroll
            for (int r = 0; r < 2; ++r)
#pragma unroll
                for (int n = 0; n < 8; ++n)
                    acc[r][n] = __builtin_amdgcn_mfma_f32_16x16x32_bf16(
                        af[r], bfr[n], acc[r][n], 0, 0, 0);
        }
    }
#pragma unroll
    for (int n = 0; n < 8; ++n) {
        int col = n * 16 + l16;
#pragma unroll
        for (int r = 0; r < 2; ++r)
#pragma unroll
            for (int reg = 0; reg < 4; ++reg) {
                int row = w * 32 + r * 16 + quad * 4 + reg;
                ctx[((size_t)(b * 1024) + qt * 128 + row) * 128 + col] =
                    acc[r][n][reg];
            }
    }
}

// K7: logits = [outs | ctx] @ fc_w.T + fc_b   (V=55, K=256)
__global__ __launch_bounds__(256, 2)
void k_fc(const unsigned short* __restrict__ outs_bf,
          const float* __restrict__ ctx,
          const float* __restrict__ fc_w, const float* __restrict__ fc_b,
          float* __restrict__ out)
{
    __shared__ float lw[55 * 257];
    __shared__ float comb[256];
    __shared__ float part[256];
    const int tid = threadIdx.x;
    const int c = tid >> 6, v = tid & 63;

    for (int idx = tid; idx < 55 * 256; idx += 256) {
        int rr = idx >> 8, cc = idx & 255;
        lw[rr * 257 + cc] = fc_w[idx];
    }
    __syncthreads();

    const int t0 = blockIdx.x * 64;
    for (int t = 0; t < 64; ++t) {
        size_t bt = (size_t)(t0 + t);
        if (tid < 128) comb[tid] = bf2f(outs_bf[bt * 128 + tid]);
        else           comb[tid] = ctx[bt * 128 + (tid - 128)];
        __syncthreads();
        float p0 = 0.f, p1 = 0.f, p2 = 0.f, p3 = 0.f;
        if (v < 55) {
            const float* wr = lw + v * 257 + c * 64;
            const float* cb = comb + c * 64;
#pragma unroll
            for (int j = 0; j < 16; ++j) {
                p0 += wr[4*j]   * cb[4*j];
                p1 += wr[4*j+1] * cb[4*j+1];
                p2 += wr[4*j+2] * cb[4*j+2];
                p3 += wr[4*j+3] * cb[4*j+3];
            }
        }
        part[tid] = (p0 + p1) + (p2 + p3);
        __syncthreads();
        if (tid < 55) {
            out[bt * 55 + tid] = fc_b[tid] + part[tid] + part[64 + tid] +
                                 part[128 + tid] + part[192 + tid];
        }
        __syncthreads();
    }
}

// ---------------------------------------------------------------------------
extern "C" void kernel_launch(void* const* d_in, const int* in_sizes, int n_in,
                              void* d_out, int out_size, void* d_ws, size_t ws_size,
                              hipStream_t stream)
{
    const int*   x      = (const int*)d_in[0];
    const float* emb    = (const float*)d_in[1];
    const float* w_ih0  = (const float*)d_in[2];
    const float* b_ih0  = (const float*)d_in[3];
    const float* w_hh0  = (const float*)d_in[4];
    const float* b_hh0  = (const float*)d_in[5];
    const float* w_ih1  = (const float*)d_in[6];
    const float* b_ih1  = (const float*)d_in[7];
    const float* w_hh1  = (const float*)d_in[8];
    const float* b_hh1  = (const float*)d_in[9];
    const float* attn_w = (const float*)d_in[10];
    const float* attn_b = (const float*)d_in[11];
    const float* fc_w   = (const float*)d_in[12];
    const float* fc_b   = (const float*)d_in[13];
    float* out = (float*)d_out;

    char* ws = (char*)d_ws;
    unsigned short* outs_bf = (unsigned short*)(ws);                        // 16 MiB
    unsigned short* outsT   = (unsigned short*)(ws + ((size_t)16 << 20));   // 16 MiB
    unsigned short* q_bf    = (unsigned short*)(ws + ((size_t)32 << 20));   // 16 MiB
    float*          ctx     = (float*)         (ws + ((size_t)48 << 20));   // 32 MiB
    float*          WEp     = (float*)         (ws + ((size_t)80 << 20));   // 28 KiB
    unsigned short* sc      = (unsigned short*)(ws + ((size_t)81 << 20));   // CB*2 MiB

    size_t fixed = (size_t)81 << 20;
    size_t avail = (ws_size > fixed) ? (ws_size - fixed) : 0;
    int CB = (int)(avail / ((size_t)2 << 20));
    if (CB < 1)  CB = 1;
    if (CB > 64) CB = 64;

    k_we<<<dim3(55), dim3(128), 0, stream>>>(emb, w_ih0, b_ih0, b_hh0, WEp);
    k_scan2<<<dim3(64), dim3(512), 0, stream>>>(
        x, WEp, w_hh0, w_ih1, b_ih1, w_hh1, b_hh1, outs_bf);
    k_transpose<<<dim3(8, 64), dim3(256), 0, stream>>>(outs_bf, outsT);
    k_qproj<<<dim3(512), dim3(256), 0, stream>>>(outs_bf, attn_w, attn_b, q_bf);

    for (int b0 = 0; b0 < 64; b0 += CB) {
        int nb = 64 - b0; if (nb > CB) nb = CB;
        k_scores <<<dim3(8, 8, nb), dim3(256), 0, stream>>>(q_bf, outs_bf, sc, b0);
        k_softmax<<<dim3(nb * 256), dim3(256), 0, stream>>>(sc);
        k_pv     <<<dim3(8, nb),   dim3(256), 0, stream>>>(sc, outsT, ctx, b0);
    }
    k_fc<<<dim3(1024), dim3(256), 0, stream>>>(outs_bf, ctx, fc_w, fc_b, out);
}